// Round 1
// baseline (3163.127 us; speedup 1.0000x reference)
//
#include <hip/hip_runtime.h>
#include <stdint.h>

#define NUM_IT 64
#define BATCH 64
#define HW 50176            // 224*224
#define CHW 150528          // 3*HW
#define NELEM 9633792       // 64*CHW
#define SIGMA 0.05f

// ---------------- Threefry-2x32, 20 rounds (JAX-exact) ----------------
__device__ __forceinline__ void tf2x32(uint32_t k0, uint32_t k1,
                                       uint32_t x0, uint32_t x1,
                                       uint32_t &o0, uint32_t &o1) {
  const uint32_t ks2 = k0 ^ k1 ^ 0x1BD11BDAu;
  x0 += k0; x1 += k1;
#define TF_R(r) { x0 += x1; x1 = (x1 << (r)) | (x1 >> (32 - (r))); x1 ^= x0; }
  TF_R(13) TF_R(15) TF_R(26) TF_R(6)
  x0 += k1;  x1 += ks2 + 1u;
  TF_R(17) TF_R(29) TF_R(16) TF_R(24)
  x0 += ks2; x1 += k0 + 2u;
  TF_R(13) TF_R(15) TF_R(26) TF_R(6)
  x0 += k0;  x1 += k1 + 3u;
  TF_R(17) TF_R(29) TF_R(16) TF_R(24)
  x0 += k1;  x1 += ks2 + 4u;
  TF_R(13) TF_R(15) TF_R(26) TF_R(6)
  x0 += ks2; x1 += k0 + 5u;
#undef TF_R
  o0 = x0; o1 = x1;
}

// bits -> uniform(-0.99999994, 1) -> sqrt(2)*erfinv (XLA/Giles f32 poly)
__device__ __forceinline__ float bits_to_normal(uint32_t bits) {
  const float LO = __uint_as_float(0xBF7FFFFFu);     // nextafter(-1,0)
  float u01 = __uint_as_float((bits >> 9) | 0x3f800000u) - 1.0f;  // [0,1)
  float u = fmaf(u01, 2.0f, LO);                     // scale folds to exactly 2.0f
  u = fmaxf(u, LO);
  // w = -log1p(-u*u); 1 - round(u*u) is exact (Sterbenz), so log(1-s) == log1p(-s).
  // __fmul_rn blocks fp-contraction: an fma(-u,u,1) here would be WRONG near |u|->1.
  float s = __fmul_rn(u, u);
  float w = -__logf(1.0f - s);
  float p;
  if (w < 5.0f) {
    float z = w - 2.5f;
    p = 2.81022636e-08f;
    p = fmaf(p, z, 3.43273939e-07f);
    p = fmaf(p, z, -3.5233877e-06f);
    p = fmaf(p, z, -4.39150654e-06f);
    p = fmaf(p, z, 0.00021858087f);
    p = fmaf(p, z, -0.00125372503f);
    p = fmaf(p, z, -0.00417768164f);
    p = fmaf(p, z, 0.246640727f);
    p = fmaf(p, z, 1.50140941f);
  } else {
    float z = sqrtf(w) - 3.0f;
    p = -0.000200214257f;
    p = fmaf(p, z, 0.000100950558f);
    p = fmaf(p, z, 0.00134934322f);
    p = fmaf(p, z, -0.00367342844f);
    p = fmaf(p, z, 0.00573950773f);
    p = fmaf(p, z, -0.0076224613f);
    p = fmaf(p, z, 0.00943887047f);
    p = fmaf(p, z, 1.00167406f);
    p = fmaf(p, z, 2.83297682f);
  }
  return 1.41421356237309515f * (p * u);
}

// base = imgs + noise (staged into d_out as scratch); zero the dot accumulators
__global__ __launch_bounds__(256) void prep_kernel(const float4* __restrict__ imgs,
                                                   const float4* __restrict__ noise,
                                                   float4* __restrict__ base,
                                                   float* __restrict__ dots) {
  int gid = blockIdx.x * 256 + threadIdx.x;          // NELEM/4 = 2408448 exactly
  float4 a = imgs[gid], b = noise[gid];
  float4 r;
  r.x = a.x + b.x; r.y = a.y + b.y; r.z = a.z + b.z; r.w = a.w + b.w;
  base[gid] = r;
  if (gid < (NUM_IT + 1) * BATCH) dots[gid] = 0.0f;
}

// Pass 1: per (iteration ii, image b): logit = dot(clip(base + t_ii), w).
// ii == NUM_IT is the no-noise lane (prob2's logit).
__global__ __launch_bounds__(256) void pass1_kernel(const float* __restrict__ base,
                                                    const float* __restrict__ wv,
                                                    float* __restrict__ dots) {
  const int chunk = blockIdx.x;   // 0..48
  const int b     = blockIdx.y;   // 0..63
  const int ii    = blockIdx.z;   // 0..64
  uint32_t kx = 0u, ky = 0u;
  if (ii < NUM_IT) tf2x32(0u, 42u, 0u, (uint32_t)ii, kx, ky);

  const int hw0 = chunk * 1024 + threadIdx.x;
  const int eb  = b * CHW;
  float sum = 0.0f;
#pragma unroll
  for (int s = 0; s < 4; ++s) {
    const int hw = hw0 + s * 256;
    float b0 = base[eb + hw];
    float b1 = base[eb + HW + hw];
    float b2 = base[eb + 2 * HW + hw];
    float w0 = wv[hw], w1 = wv[HW + hw], w2 = wv[2 * HW + hw];
    float a0 = b0, a1 = b1, a2 = b2;
    if (ii < NUM_IT) {
      uint32_t o0, o1;
      const uint32_t e = (uint32_t)(eb + hw);
      tf2x32(kx, ky, 0u, e,            o0, o1); float t0 = bits_to_normal(o0 ^ o1);
      tf2x32(kx, ky, 0u, e + HW,       o0, o1); float t1 = bits_to_normal(o0 ^ o1);
      tf2x32(kx, ky, 0u, e + 2u * HW,  o0, o1); float t2 = bits_to_normal(o0 ^ o1);
      float mu = (t0 + t1 + t2) * (1.0f / 3.0f);
      float d0 = t0 - mu, d1 = t1 - mu, d2 = t2 - mu;
      float var = (d0 * d0 + d1 * d1 + d2 * d2) * 0.5f;   // ddof=1 over 3
      float sc = SIGMA / sqrtf(var);
      a0 = fmaf(d0, sc, b0); a1 = fmaf(d1, sc, b1); a2 = fmaf(d2, sc, b2);
    }
    a0 = fminf(fmaxf(a0, 0.0f), 1.0f);
    a1 = fminf(fmaxf(a1, 0.0f), 1.0f);
    a2 = fminf(fmaxf(a2, 0.0f), 1.0f);
    sum = fmaf(a0, w0, sum);
    sum = fmaf(a1, w1, sum);
    sum = fmaf(a2, w2, sum);
  }
  // block reduce: 4 waves of 64
  for (int off = 32; off > 0; off >>= 1) sum += __shfl_down(sum, off, 64);
  __shared__ float red[4];
  if ((threadIdx.x & 63) == 0) red[threadIdx.x >> 6] = sum;
  __syncthreads();
  if (threadIdx.x == 0)
    atomicAdd(&dots[ii * BATCH + b], red[0] + red[1] + red[2] + red[3]);
}

// coef[b][i] = (sigmoid(logit2)-sigmoid(logit_i)) / (NUM*SIGMA*(sqrt(nc)+eps))
__global__ void coef_kernel(const float* __restrict__ dots,
                            const float* __restrict__ bptr,
                            float* __restrict__ coef) {
  const int b = threadIdx.x;  // 64 threads
  const float bias = bptr[0];
  const float p2 = 1.0f / (1.0f + expf(-(dots[NUM_IT * BATCH + b] + bias)));
  float nc = 0.0f;
  for (int i = 0; i < NUM_IT; ++i) {
    float ap = 1.0f / (1.0f + expf(-(dots[i * BATCH + b] + bias)));
    float d = p2 - ap;
    nc += d * d;
  }
  const float inv = 1.0f / ((float)NUM_IT * SIGMA * (sqrtf(nc) + 1e-10f));
  for (int i = 0; i < NUM_IT; ++i) {
    float ap = 1.0f / (1.0f + expf(-(dots[i * BATCH + b] + bias)));
    float d = p2 - ap;
    coef[b * NUM_IT + i] = d * inv;
  }
}

// Pass 2: out[e] = sum_i t_norm_i[e] * coef[b][i]; t regenerated, base not needed.
__global__ __launch_bounds__(256) void pass2_kernel(float* __restrict__ out,
                                                    const float* __restrict__ coef) {
  __shared__ float cf[NUM_IT];
  __shared__ uint32_t kxs[NUM_IT], kys[NUM_IT];
  const int b = blockIdx.y;
  if (threadIdx.x < NUM_IT) {
    uint32_t kx, ky;
    tf2x32(0u, 42u, 0u, (uint32_t)threadIdx.x, kx, ky);
    kxs[threadIdx.x] = kx; kys[threadIdx.x] = ky;
    cf[threadIdx.x] = coef[b * NUM_IT + threadIdx.x];
  }
  __syncthreads();
  const int hw0 = blockIdx.x * 1024 + threadIdx.x;
  const int eb  = b * CHW;
  float acc[4][3];
#pragma unroll
  for (int s = 0; s < 4; ++s) { acc[s][0] = 0.f; acc[s][1] = 0.f; acc[s][2] = 0.f; }

#pragma unroll 1
  for (int i = 0; i < NUM_IT; ++i) {
    const uint32_t kx = kxs[i], ky = kys[i];
    const float ci = cf[i];
#pragma unroll
    for (int s = 0; s < 4; ++s) {
      const uint32_t e = (uint32_t)(eb + hw0 + s * 256);
      uint32_t o0, o1;
      tf2x32(kx, ky, 0u, e,           o0, o1); float t0 = bits_to_normal(o0 ^ o1);
      tf2x32(kx, ky, 0u, e + HW,      o0, o1); float t1 = bits_to_normal(o0 ^ o1);
      tf2x32(kx, ky, 0u, e + 2u * HW, o0, o1); float t2 = bits_to_normal(o0 ^ o1);
      float mu = (t0 + t1 + t2) * (1.0f / 3.0f);
      float d0 = t0 - mu, d1 = t1 - mu, d2 = t2 - mu;
      float var = (d0 * d0 + d1 * d1 + d2 * d2) * 0.5f;
      float g = (SIGMA / sqrtf(var)) * ci;
      acc[s][0] = fmaf(d0, g, acc[s][0]);
      acc[s][1] = fmaf(d1, g, acc[s][1]);
      acc[s][2] = fmaf(d2, g, acc[s][2]);
    }
  }
#pragma unroll
  for (int s = 0; s < 4; ++s) {
    const int hw = hw0 + s * 256;
    out[eb + hw]          = acc[s][0];
    out[eb + HW + hw]     = acc[s][1];
    out[eb + 2 * HW + hw] = acc[s][2];
  }
}

extern "C" void kernel_launch(void* const* d_in, const int* in_sizes, int n_in,
                              void* d_out, int out_size, void* d_ws, size_t ws_size,
                              hipStream_t stream) {
  const float* imgs  = (const float*)d_in[0];
  const float* noise = (const float*)d_in[1];
  const float* wv    = (const float*)d_in[2];
  const float* bptr  = (const float*)d_in[3];
  float* out  = (float*)d_out;
  float* dots = (float*)d_ws;                       // (NUM_IT+1)*BATCH floats
  float* coef = dots + (NUM_IT + 1) * BATCH;        // BATCH*NUM_IT floats

  // Stage base = imgs + noise into d_out (scratch until pass2 overwrites it).
  prep_kernel<<<dim3(NELEM / 1024), dim3(256), 0, stream>>>(
      (const float4*)imgs, (const float4*)noise, (float4*)out, dots);
  pass1_kernel<<<dim3(49, BATCH, NUM_IT + 1), dim3(256), 0, stream>>>(out, wv, dots);
  coef_kernel<<<dim3(1), dim3(64), 0, stream>>>(dots, bptr, coef);
  pass2_kernel<<<dim3(49, BATCH), dim3(256), 0, stream>>>(out, coef);
}